// Round 1
// baseline (701.400 us; speedup 1.0000x reference)
//
#include <hip/hip_runtime.h>
#include <math.h>

#define LEAK 0.01f

// ---------------------------------------------------------------------------
// Geometry constants
//   high_level: [4,256,128,128]  low_level: [4,64,256,256]  emb: [4,256,256,256]
//   H = W = 256, 65536 px/image, 262144 px total
// ---------------------------------------------------------------------------

// ws layout (float indices):
//   cat  : [262144][64]  at 0          (16,777,216 floats)
//   pre  : [262144][16]  at 16777216   ( 4,194,304 floats)
//   wbuf : transposed weights at 20971520:
//     rwt [128][64]  +0      (8192)   rwt[c][o] = reduce_w[o*128+c]
//     c1t [64][16]   +8192   (1024)   c1t[c][j] = conv1_w[j*64+c]
//     ect [256][16]  +9216   (4096)   ect[c][j] = embconv_w[j*256+c]
//     w2t [9][16][36]+13312  (5184)   w2t[k][i][o] = conv2_w[o][i][ky][kx], k=ky*3+kx
//     owt [64][32]   +18496  (2048)   owt[c][o] = out_w[o*64+c]
#define WS_PRE_OFF 16777216
#define WS_W_OFF   20971520

__global__ __launch_bounds__(256) void k0_transpose(
    const float* __restrict__ reduce_w, const float* __restrict__ conv1_w,
    const float* __restrict__ embconv_w, const float* __restrict__ conv2_w,
    const float* __restrict__ out_w, float* __restrict__ wbuf) {
  int idx = blockIdx.x * 256 + threadIdx.x;
  if (idx < 8192) {
    int c = idx >> 6, o = idx & 63;
    wbuf[idx] = reduce_w[o * 128 + c];
  } else if (idx < 9216) {
    int i2 = idx - 8192; int c = i2 >> 4, j = i2 & 15;
    wbuf[idx] = conv1_w[j * 64 + c];
  } else if (idx < 13312) {
    int i2 = idx - 9216; int c = i2 >> 4, j = i2 & 15;
    wbuf[idx] = embconv_w[j * 256 + c];
  } else if (idx < 18496) {
    int i2 = idx - 13312;
    int o = i2 % 36; int r = i2 / 36; int i = r & 15; int kk = r >> 4;
    wbuf[idx] = conv2_w[(o * 16 + i) * 9 + kk];
  } else if (idx < 20544) {
    int i2 = idx - 18496; int c = i2 >> 5, o = i2 & 31;
    wbuf[idx] = out_w[o * 64 + c];
  }
}

// ---------------------------------------------------------------------------
// KA: fused pixel_shuffle + concat + reduce(128->64) + conv1(64->16)
//     + embconv(256->16) + leaky  ->  cat (NHWC64), pre (NHWC16)
// 1 pixel per thread. Weight reads are wave-uniform -> SMEM (s_load).
// ---------------------------------------------------------------------------
__global__ __launch_bounds__(256) void ka_fused(
    const float* __restrict__ high, const float* __restrict__ low,
    const float* __restrict__ emb,
    const float* __restrict__ reduce_b, const float* __restrict__ conv1_b,
    const float* __restrict__ embconv_b,
    const float* __restrict__ wbuf,
    float* __restrict__ cat_out, float* __restrict__ pre_out) {
  const float* rwt = wbuf;              // [128][64]
  const float* c1t = wbuf + 8192;       // [64][16]
  const float* ect = wbuf + 9216;       // [256][16]

  int pix = blockIdx.x * 256 + threadIdx.x;
  int b   = pix >> 16;
  int rem = pix & 65535;
  int y   = rem >> 8, x = rem & 255;

  float acc[64];
#pragma unroll
  for (int o = 0; o < 64; ++o) acc[o] = reduce_b[o];

  // ---- reduce: pixel_shuffle(high) channels 0..63 ----
  // ps(high)[c][y][x] = high[b, c*4 + (y&1)*2 + (x&1), y>>1, x>>1]
  int lane_off = ((x & 1) << 14) + (x >> 1);                       // plane 128*128
  int hb = (b * 256 + ((y & 1) << 1)) * 16384 + ((y >> 1) << 7);   // + c*65536
#pragma unroll 4
  for (int c = 0; c < 64; ++c) {
    float xv = high[hb + c * 65536 + lane_off];
    const float* wr = rwt + c * 64;
#pragma unroll
    for (int o4 = 0; o4 < 16; ++o4) {
      float4 w = *(const float4*)(wr + o4 * 4);
      acc[o4 * 4 + 0] = fmaf(w.x, xv, acc[o4 * 4 + 0]);
      acc[o4 * 4 + 1] = fmaf(w.y, xv, acc[o4 * 4 + 1]);
      acc[o4 * 4 + 2] = fmaf(w.z, xv, acc[o4 * 4 + 2]);
      acc[o4 * 4 + 3] = fmaf(w.w, xv, acc[o4 * 4 + 3]);
    }
  }
  // ---- reduce: low channels 64..127 ----
  int lb = b * 64 * 65536 + rem;
#pragma unroll 4
  for (int c = 0; c < 64; ++c) {
    float xv = low[lb + c * 65536];
    const float* wr = rwt + (64 + c) * 64;
#pragma unroll
    for (int o4 = 0; o4 < 16; ++o4) {
      float4 w = *(const float4*)(wr + o4 * 4);
      acc[o4 * 4 + 0] = fmaf(w.x, xv, acc[o4 * 4 + 0]);
      acc[o4 * 4 + 1] = fmaf(w.y, xv, acc[o4 * 4 + 1]);
      acc[o4 * 4 + 2] = fmaf(w.z, xv, acc[o4 * 4 + 2]);
      acc[o4 * 4 + 3] = fmaf(w.w, xv, acc[o4 * 4 + 3]);
    }
  }

  // ---- store cat (NHWC, 64ch) ----
  {
    float* cp = cat_out + (size_t)pix * 64;
#pragma unroll
    for (int o4 = 0; o4 < 16; ++o4) {
      float4 v;
      v.x = acc[o4 * 4 + 0]; v.y = acc[o4 * 4 + 1];
      v.z = acc[o4 * 4 + 2]; v.w = acc[o4 * 4 + 3];
      *(float4*)(cp + o4 * 4) = v;
    }
  }

  // ---- conv1(cat) + embconv(emb) -> pre (16) ----
  float pre[16];
#pragma unroll
  for (int j = 0; j < 16; ++j) pre[j] = conv1_b[j] + embconv_b[j];

#pragma unroll
  for (int c = 0; c < 64; ++c) {
    float xv = acc[c];
    const float* wr = c1t + c * 16;
#pragma unroll
    for (int j4 = 0; j4 < 4; ++j4) {
      float4 w = *(const float4*)(wr + j4 * 4);
      pre[j4 * 4 + 0] = fmaf(w.x, xv, pre[j4 * 4 + 0]);
      pre[j4 * 4 + 1] = fmaf(w.y, xv, pre[j4 * 4 + 1]);
      pre[j4 * 4 + 2] = fmaf(w.z, xv, pre[j4 * 4 + 2]);
      pre[j4 * 4 + 3] = fmaf(w.w, xv, pre[j4 * 4 + 3]);
    }
  }

  int eb = b * 256 * 65536 + rem;
#pragma unroll 4
  for (int c = 0; c < 256; ++c) {
    float xv = emb[eb + c * 65536];
    const float* wr = ect + c * 16;
#pragma unroll
    for (int j4 = 0; j4 < 4; ++j4) {
      float4 w = *(const float4*)(wr + j4 * 4);
      pre[j4 * 4 + 0] = fmaf(w.x, xv, pre[j4 * 4 + 0]);
      pre[j4 * 4 + 1] = fmaf(w.y, xv, pre[j4 * 4 + 1]);
      pre[j4 * 4 + 2] = fmaf(w.z, xv, pre[j4 * 4 + 2]);
      pre[j4 * 4 + 3] = fmaf(w.w, xv, pre[j4 * 4 + 3]);
    }
  }

  // ---- leaky + store pre (NHWC, 16ch) ----
  {
    float* pp = pre_out + (size_t)pix * 16;
#pragma unroll
    for (int j4 = 0; j4 < 4; ++j4) {
      float4 v;
      float a0 = pre[j4 * 4 + 0], a1 = pre[j4 * 4 + 1];
      float a2 = pre[j4 * 4 + 2], a3 = pre[j4 * 4 + 3];
      v.x = a0 > 0.f ? a0 : a0 * LEAK;
      v.y = a1 > 0.f ? a1 : a1 * LEAK;
      v.z = a2 > 0.f ? a2 : a2 * LEAK;
      v.w = a3 > 0.f ? a3 : a3 * LEAK;
      *(float4*)(pp + j4 * 4) = v;
    }
  }
}

// ---------------------------------------------------------------------------
// KB: conv2 3x3 (16->36) + grouped local aggregation + out 1x1 (64->32)
//     + BN + leaky -> d_out (NCHW)
// 16x16 pixel tile per block; pre staged in LDS channel-major [16][18*18].
// ---------------------------------------------------------------------------
__global__ __launch_bounds__(256) void kb_fused(
    const float* __restrict__ cat_in, const float* __restrict__ pre_in,
    const float* __restrict__ wbuf,
    const float* __restrict__ conv2_b, const float* __restrict__ out_b,
    const float* __restrict__ bn_gamma, const float* __restrict__ bn_beta,
    const float* __restrict__ bn_mean, const float* __restrict__ bn_var,
    float* __restrict__ out) {
  const float* w2t = wbuf + 13312;  // [9][16][36]
  const float* owt = wbuf + 18496;  // [64][32]

  __shared__ float lds_pre[16][324];  // [ch][18*18]

  int tid = threadIdx.x;
  int bx = blockIdx.x & 15, by = (blockIdx.x >> 4) & 15, b = blockIdx.x >> 8;
  int x0 = bx << 4, y0 = by << 4;
  int tx = tid & 15, ty = tid >> 4;

  // ---- stage pre tile (18x18 with zero halo) ----
  for (int s = tid; s < 324; s += 256) {
    int sy = s / 18, sx = s - sy * 18;
    int gy = y0 + sy - 1, gx = x0 + sx - 1;
    float4 p0 = {0.f, 0.f, 0.f, 0.f}, p1 = p0, p2 = p0, p3 = p0;
    if ((unsigned)gy < 256u && (unsigned)gx < 256u) {
      const float* pp = pre_in + (size_t)((b * 256 + gy) * 256 + gx) * 16;
      p0 = *(const float4*)(pp + 0);
      p1 = *(const float4*)(pp + 4);
      p2 = *(const float4*)(pp + 8);
      p3 = *(const float4*)(pp + 12);
    }
    lds_pre[0][s] = p0.x;  lds_pre[1][s] = p0.y;
    lds_pre[2][s] = p0.z;  lds_pre[3][s] = p0.w;
    lds_pre[4][s] = p1.x;  lds_pre[5][s] = p1.y;
    lds_pre[6][s] = p1.z;  lds_pre[7][s] = p1.w;
    lds_pre[8][s] = p2.x;  lds_pre[9][s] = p2.y;
    lds_pre[10][s] = p2.z; lds_pre[11][s] = p2.w;
    lds_pre[12][s] = p3.x; lds_pre[13][s] = p3.y;
    lds_pre[14][s] = p3.z; lds_pre[15][s] = p3.w;
  }
  __syncthreads();

  int px = x0 + tx, py = y0 + ty;

  // ---- conv2: weight[36] ----
  float wgt[36];
#pragma unroll
  for (int o = 0; o < 36; ++o) wgt[o] = conv2_b[o];

  for (int k = 0; k < 9; ++k) {  // rolled: keeps code size down; wgt[o] static
    int ky = k / 3, kx = k - ky * 3;
    int slot = (ty + ky) * 18 + (tx + kx);
    float pv[16];
#pragma unroll
    for (int i = 0; i < 16; ++i) pv[i] = lds_pre[i][slot];
    const float* wp = w2t + k * 576;
#pragma unroll
    for (int i = 0; i < 16; ++i) {
      float xv = pv[i];
#pragma unroll
      for (int o4 = 0; o4 < 9; ++o4) {
        float4 w = *(const float4*)(wp + i * 36 + o4 * 4);
        wgt[o4 * 4 + 0] = fmaf(w.x, xv, wgt[o4 * 4 + 0]);
        wgt[o4 * 4 + 1] = fmaf(w.y, xv, wgt[o4 * 4 + 1]);
        wgt[o4 * 4 + 2] = fmaf(w.z, xv, wgt[o4 * 4 + 2]);
        wgt[o4 * 4 + 3] = fmaf(w.w, xv, wgt[o4 * 4 + 3]);
      }
    }
  }

  // ---- grouped local aggregation: agg[64] ----
  float agg[64];
#pragma unroll
  for (int c = 0; c < 64; ++c) agg[c] = 0.f;

#pragma unroll
  for (int k = 0; k < 9; ++k) {  // unrolled: wgt[g*9+k] must be static
    int ky = k / 3, kx = k - ky * 3;
    int gy = py + ky - 1, gx = px + kx - 1;
    bool valid = ((unsigned)gy < 256u) && ((unsigned)gx < 256u);
    int cgy = gy < 0 ? 0 : (gy > 255 ? 255 : gy);
    int cgx = gx < 0 ? 0 : (gx > 255 ? 255 : gx);
    const float* cp = cat_in + (size_t)((b * 256 + cgy) * 256 + cgx) * 64;
    float wk0 = valid ? wgt[0 * 9 + k] : 0.f;
    float wk1 = valid ? wgt[1 * 9 + k] : 0.f;
    float wk2 = valid ? wgt[2 * 9 + k] : 0.f;
    float wk3 = valid ? wgt[3 * 9 + k] : 0.f;
#pragma unroll
    for (int c4 = 0; c4 < 16; ++c4) {
      float4 cv = *(const float4*)(cp + c4 * 4);
      float wk = (c4 < 4) ? wk0 : (c4 < 8) ? wk1 : (c4 < 12) ? wk2 : wk3;
      agg[c4 * 4 + 0] = fmaf(wk, cv.x, agg[c4 * 4 + 0]);
      agg[c4 * 4 + 1] = fmaf(wk, cv.y, agg[c4 * 4 + 1]);
      agg[c4 * 4 + 2] = fmaf(wk, cv.z, agg[c4 * 4 + 2]);
      agg[c4 * 4 + 3] = fmaf(wk, cv.w, agg[c4 * 4 + 3]);
    }
  }

  // ---- out conv (64->32) ----
  float o32[32];
#pragma unroll
  for (int o = 0; o < 32; ++o) o32[o] = out_b[o];
#pragma unroll
  for (int c = 0; c < 64; ++c) {
    float xv = agg[c];
    const float* wr = owt + c * 32;
#pragma unroll
    for (int o4 = 0; o4 < 8; ++o4) {
      float4 w = *(const float4*)(wr + o4 * 4);
      o32[o4 * 4 + 0] = fmaf(w.x, xv, o32[o4 * 4 + 0]);
      o32[o4 * 4 + 1] = fmaf(w.y, xv, o32[o4 * 4 + 1]);
      o32[o4 * 4 + 2] = fmaf(w.z, xv, o32[o4 * 4 + 2]);
      o32[o4 * 4 + 3] = fmaf(w.w, xv, o32[o4 * 4 + 3]);
    }
  }

  // ---- BN (eval) + leaky + store NCHW ----
  int outbase = (b * 32 * 256 + py) * 256 + px;
#pragma unroll
  for (int o = 0; o < 32; ++o) {
    float sc = bn_gamma[o] / sqrtf(bn_var[o] + 1e-5f);
    float v = (o32[o] - bn_mean[o]) * sc + bn_beta[o];
    v = v > 0.f ? v : v * LEAK;
    out[outbase + o * 65536] = v;
  }
}

// ---------------------------------------------------------------------------
extern "C" void kernel_launch(void* const* d_in, const int* in_sizes, int n_in,
                              void* d_out, int out_size, void* d_ws, size_t ws_size,
                              hipStream_t stream) {
  const float* high      = (const float*)d_in[0];
  const float* low       = (const float*)d_in[1];
  const float* emb       = (const float*)d_in[2];
  const float* reduce_w  = (const float*)d_in[3];
  const float* reduce_b  = (const float*)d_in[4];
  const float* conv1_w   = (const float*)d_in[5];
  const float* conv1_b   = (const float*)d_in[6];
  const float* embconv_w = (const float*)d_in[7];
  const float* embconv_b = (const float*)d_in[8];
  const float* conv2_w   = (const float*)d_in[9];
  const float* conv2_b   = (const float*)d_in[10];
  const float* out_w     = (const float*)d_in[11];
  const float* out_b     = (const float*)d_in[12];
  const float* bn_gamma  = (const float*)d_in[13];
  const float* bn_beta   = (const float*)d_in[14];
  const float* bn_mean   = (const float*)d_in[15];
  const float* bn_var    = (const float*)d_in[16];

  float* ws   = (float*)d_ws;
  float* cat  = ws;                // 16,777,216 floats
  float* pre  = ws + WS_PRE_OFF;   //  4,194,304 floats
  float* wbuf = ws + WS_W_OFF;     //     20,544 floats

  k0_transpose<<<81, 256, 0, stream>>>(reduce_w, conv1_w, embconv_w, conv2_w,
                                       out_w, wbuf);
  ka_fused<<<1024, 256, 0, stream>>>(high, low, emb, reduce_b, conv1_b,
                                     embconv_b, wbuf, cat, pre);
  kb_fused<<<1024, 256, 0, stream>>>(cat, pre, wbuf, conv2_b, out_b, bn_gamma,
                                     bn_beta, bn_mean, bn_var, (float*)d_out);
}